// Round 2
// baseline (1275.904 us; speedup 1.0000x reference)
//
#include <hip/hip_runtime.h>

#define EPS_BN 1e-5f
#define NEG_SLOPE 0.01f

// ---- degree count: one int atomic per edge (self-loops added analytically) ----
__global__ void deg_count_kernel(const int* __restrict__ dst, int* __restrict__ cnt, int E) {
    int e = blockIdx.x * blockDim.x + threadIdx.x;
    if (e < E) atomicAdd(&cnt[dst[e]], 1);
}

// in-place: int count -> float rsqrt(count + 1)   (+1 = self loop; always > 0)
__global__ void dinv_kernel(float* __restrict__ buf, int N) {
    int i = blockIdx.x * blockDim.x + threadIdx.x;
    if (i < N) {
        int c = ((const int*)buf)[i];
        buf[i] = rsqrtf((float)(c + 1));
    }
}

// ---- tiny dense GEMM: T[N,Fout] = H[N,Fin] @ W[Fin,Fout], W staged in LDS ----
__global__ void gemm_kernel(const float* __restrict__ H, const float* __restrict__ W,
                            float* __restrict__ T, int N, int Fin, int Fout) {
    extern __shared__ float sW[];
    for (int i = threadIdx.x; i < Fin * Fout; i += blockDim.x) sW[i] = W[i];
    __syncthreads();
    int npb = blockDim.x / Fout;
    int node = blockIdx.x * npb + (int)(threadIdx.x / Fout);
    int f = threadIdx.x % Fout;
    if (node >= N) return;
    const float* h = H + (size_t)node * Fin;
    float acc = 0.f;
    for (int k = 0; k < Fin; ++k) acc = fmaf(h[k], sW[k * Fout + f], acc);
    T[(size_t)node * Fout + f] = acc;
}

// ---- edge scatter: agg[dst,f] += T[src,f] * dinv[src]*dinv[dst] ----
// one lane per (edge, feature); F = 1<<logF lanes per edge -> coalesced rows
__global__ void scatter_kernel(const float* __restrict__ T, const int* __restrict__ src,
                               const int* __restrict__ dst, const float* __restrict__ dinv,
                               float* __restrict__ agg, int E, int logF) {
    int tid = blockIdx.x * blockDim.x + threadIdx.x;
    int e = tid >> logF;
    if (e >= E) return;
    int f = tid & ((1 << logF) - 1);
    int s = src[e], d = dst[e];
    float nrm = dinv[s] * dinv[d];
    atomicAdd(&agg[((size_t)d << logF) + f], T[((size_t)s << logF) + f] * nrm);
}

// ---- fused: self-loop term + bias + BN(inference) + LeakyReLU, in place ----
__global__ void bn_fuse_kernel(float* __restrict__ agg, const float* __restrict__ T,
                               const float* __restrict__ dinv,
                               const float* __restrict__ b, const float* __restrict__ gamma,
                               const float* __restrict__ beta, const float* __restrict__ rm,
                               const float* __restrict__ rv, int N, int logF) {
    int tid = blockIdx.x * blockDim.x + threadIdx.x;
    int node = tid >> logF;
    if (node >= N) return;
    int f = tid & ((1 << logF) - 1);
    float di = dinv[node];
    float pre = agg[tid] + T[tid] * di * di + b[f];
    float y = (pre - rm[f]) * rsqrtf(rv[f] + EPS_BN) * gamma[f] + beta[f];
    agg[tid] = (y >= 0.f) ? y : NEG_SLOPE * y;
}

// ---- mean pool: atomic scatter by graph id (batch sorted, 8192 hot addresses) ----
__global__ void pool_kernel(const float* __restrict__ h, const int* __restrict__ batch,
                            float* __restrict__ out, float* __restrict__ gcnt, int N) {
    int tid = blockIdx.x * blockDim.x + threadIdx.x;
    int node = tid >> 5;
    if (node >= N) return;
    int f = tid & 31;
    int g = batch[node];
    atomicAdd(&out[((size_t)g << 5) + f], h[tid]);
    if (f == 0) atomicAdd(&gcnt[g], 1.0f);
}

__global__ void pool_div_kernel(float* __restrict__ out, const float* __restrict__ gcnt, int G) {
    int tid = blockIdx.x * blockDim.x + threadIdx.x;
    if (tid < (G << 5)) out[tid] /= fmaxf(gcnt[tid >> 5], 1.0f);
}

extern "C" void kernel_launch(void* const* d_in, const int* in_sizes, int n_in,
                              void* d_out, int out_size, void* d_ws, size_t ws_size,
                              hipStream_t stream) {
    const float* x   = (const float*)d_in[0];
    const float* W1  = (const float*)d_in[1];
    const float* b1  = (const float*)d_in[2];
    const float* g1  = (const float*)d_in[3];
    const float* be1 = (const float*)d_in[4];
    const float* rm1 = (const float*)d_in[5];
    const float* rv1 = (const float*)d_in[6];
    const float* W2  = (const float*)d_in[7];
    const float* b2  = (const float*)d_in[8];
    const float* g2  = (const float*)d_in[9];
    const float* be2 = (const float*)d_in[10];
    const float* rm2 = (const float*)d_in[11];
    const float* rv2 = (const float*)d_in[12];
    const float* W3  = (const float*)d_in[13];
    const float* b3  = (const float*)d_in[14];
    const float* g3  = (const float*)d_in[15];
    const float* be3 = (const float*)d_in[16];
    const float* rm3 = (const float*)d_in[17];
    const float* rv3 = (const float*)d_in[18];
    const int* ei    = (const int*)d_in[19];
    const int* batch = (const int*)d_in[20];

    const int N = in_sizes[0] / 3;
    const int E = in_sizes[19] / 2;
    const int G = out_size / 32;
    const int* src = ei;
    const int* dst = ei + E;

    float* ws   = (float*)d_ws;
    float* dinv = ws;                               // N floats (int counts first)
    float* bufA = ws + N;                           // N*64
    float* bufB = bufA + (size_t)N * 64;            // N*64
    float* gcnt = bufB + (size_t)N * 64;            // G
    float* out  = (float*)d_out;

    const int B = 256;

    // degrees -> dinv
    hipMemsetAsync(dinv, 0, (size_t)N * 4, stream);
    deg_count_kernel<<<(E + B - 1) / B, B, 0, stream>>>(dst, (int*)dinv, E);
    dinv_kernel<<<(N + B - 1) / B, B, 0, stream>>>(dinv, N);

    // ---- layer 1: x(N,3) @ W1 -> bufA(N,64); scatter -> bufB; bn in place ----
    gemm_kernel<<<(N + 3) / 4, B, 3 * 64 * 4, stream>>>(x, W1, bufA, N, 3, 64);
    hipMemsetAsync(bufB, 0, (size_t)N * 64 * 4, stream);
    scatter_kernel<<<(int)(((size_t)E * 64 + B - 1) / B), B, 0, stream>>>(bufA, src, dst, dinv, bufB, E, 6);
    bn_fuse_kernel<<<(int)(((size_t)N * 64 + B - 1) / B), B, 0, stream>>>(bufB, bufA, dinv, b1, g1, be1, rm1, rv1, N, 6);

    // ---- layer 2: bufB(N,64) @ W2 -> bufA(N,64) ----
    gemm_kernel<<<(N + 3) / 4, B, 64 * 64 * 4, stream>>>(bufB, W2, bufA, N, 64, 64);
    hipMemsetAsync(bufB, 0, (size_t)N * 64 * 4, stream);
    scatter_kernel<<<(int)(((size_t)E * 64 + B - 1) / B), B, 0, stream>>>(bufA, src, dst, dinv, bufB, E, 6);
    bn_fuse_kernel<<<(int)(((size_t)N * 64 + B - 1) / B), B, 0, stream>>>(bufB, bufA, dinv, b2, g2, be2, rm2, rv2, N, 6);

    // ---- layer 3: bufB(N,64) @ W3 -> bufA(N,32) ----
    gemm_kernel<<<(N + 7) / 8, B, 64 * 32 * 4, stream>>>(bufB, W3, bufA, N, 64, 32);
    hipMemsetAsync(bufB, 0, (size_t)N * 32 * 4, stream);
    scatter_kernel<<<(int)(((size_t)E * 32 + B - 1) / B), B, 0, stream>>>(bufA, src, dst, dinv, bufB, E, 5);
    bn_fuse_kernel<<<(int)(((size_t)N * 32 + B - 1) / B), B, 0, stream>>>(bufB, bufA, dinv, b3, g3, be3, rm3, rv3, N, 5);

    // ---- mean pool ----
    hipMemsetAsync(out, 0, (size_t)G * 32 * 4, stream);
    hipMemsetAsync(gcnt, 0, (size_t)G * 4, stream);
    pool_kernel<<<(int)(((size_t)N * 32 + B - 1) / B), B, 0, stream>>>(bufB, batch, out, gcnt, N);
    pool_div_kernel<<<(G * 32 + B - 1) / B, B, 0, stream>>>(out, gcnt, G);
}